// Round 12
// baseline (1697.709 us; speedup 1.0000x reference)
//
#include <hip/hip_runtime.h>
#include <hip/hip_bf16.h>

typedef __bf16 bf16_t;
typedef bf16_t bf16x8 __attribute__((ext_vector_type(8)));
typedef bf16_t bf16x4 __attribute__((ext_vector_type(4)));
typedef float f32x4 __attribute__((ext_vector_type(4)));

typedef const __attribute__((address_space(1))) void GV;
typedef __attribute__((address_space(3))) void LV;

__device__ __forceinline__ void gload_lds16(const bf16_t* gsrc, bf16_t* ldst) {
    __builtin_amdgcn_global_load_lds((GV*)gsrc, (LV*)ldst, 16, 0, 0);
}

// ---------------- prep: 6 weight transposes (bid<10240) + 6 modsig linears (bid>=10240)
__global__ __launch_bounds__(256) void prep_kernel(
    const float* __restrict__ wq, const float* __restrict__ wk, const float* __restrict__ wv,
    const float* __restrict__ lvw, const float* __restrict__ f1w, const float* __restrict__ f2w,
    bf16_t* __restrict__ wqT, bf16_t* __restrict__ lvwT,
    bf16_t* __restrict__ f1wT, bf16_t* __restrict__ f2wT,
    const float* __restrict__ cond,
    const float* __restrict__ mw0, const float* __restrict__ mw1, const float* __restrict__ mw2,
    const float* __restrict__ mw3, const float* __restrict__ mw4, const float* __restrict__ mw5,
    const float* __restrict__ mc0, const float* __restrict__ mc1, const float* __restrict__ mc2,
    const float* __restrict__ mc3, const float* __restrict__ mc4, const float* __restrict__ mc5,
    float* __restrict__ mod)
{
    __shared__ float sbuf[32 * 33];
    const int bid = blockIdx.x;
    if (bid < 10240) {
        float (*tile)[33] = (float(*)[33])sbuf;
        const float* in; bf16_t* out; int N, nx, K, local;
        if (bid < 6144) {
            const int sec = bid >> 11;
            local = bid & 2047;
            in = (sec == 0) ? wq : ((sec == 1) ? wk : wv);
            out = wqT + (long long)sec * 2097152;
            K = 512; N = 4096; nx = 128;
        } else if (bid < 8192) {
            local = bid - 6144; in = lvw; out = lvwT; K = 4096; N = 512; nx = 16;
        } else if (bid < 9216) {
            local = bid - 8192; in = f1w; out = f1wT; K = 512; N = 2048; nx = 64;
        } else {
            local = bid - 9216; in = f2w; out = f2wT; K = 2048; N = 512; nx = 16;
        }
        const int n0 = (local % nx) * 32, k0 = (local / nx) * 32;
        const int tx = threadIdx.x & 31, ty = threadIdx.x >> 5;
#pragma unroll
        for (int i = 0; i < 32; i += 8)
            tile[ty + i][tx] = in[(long long)(k0 + ty + i) * N + n0 + tx];
        __syncthreads();
#pragma unroll
        for (int i = 0; i < 32; i += 8)
            out[(long long)(n0 + ty + i) * K + k0 + tx] = (bf16_t)tile[tx][ty + i];
    } else {
        float* cs = sbuf;
        const int lb = bid - 10240;
        const int sig = lb >> 3, b = lb & 7;
        const float* w; const float* bi;
        switch (sig) {
            case 0: w = mw0; bi = mc0; break;
            case 1: w = mw1; bi = mc1; break;
            case 2: w = mw2; bi = mc2; break;
            case 3: w = mw3; bi = mc3; break;
            case 4: w = mw4; bi = mc4; break;
            default: w = mw5; bi = mc5; break;
        }
        for (int i = threadIdx.x; i < 512; i += 256) cs[i] = cond[b * 512 + i];
        __syncthreads();
        for (int n = threadIdx.x; n < 512; n += 256) {
            float s0 = 0.f, s1 = 0.f, s2 = 0.f, s3 = 0.f;
            for (int i = 0; i < 512; i += 4) {
                s0 = fmaf(cs[i], w[(long long)i * 512 + n], s0);
                s1 = fmaf(cs[i + 1], w[(long long)(i + 1) * 512 + n], s1);
                s2 = fmaf(cs[i + 2], w[(long long)(i + 2) * 512 + n], s2);
                s3 = fmaf(cs[i + 3], w[(long long)(i + 3) * 512 + n], s3);
            }
            mod[(long long)(sig * 8 + b) * 512 + n] = bi[n] + (s0 + s1) + (s2 + s3);
        }
    }
}

// ---------------- fused LayerNorm + AdaLN modulate, fp32 -> bf16
__global__ __launch_bounds__(128) void ln_mod_kernel(
    const float* __restrict__ x, const float* __restrict__ g, const float* __restrict__ be,
    const float* __restrict__ gamma, const float* __restrict__ beta, bf16_t* __restrict__ out)
{
    const int row = blockIdx.x;
    const int b = row >> 10;
    const int t = threadIdx.x;
    const float4 v = reinterpret_cast<const float4*>(x + (long long)row * 512)[t];
    float s = v.x + v.y + v.z + v.w;
    float ss = v.x * v.x + v.y * v.y + v.z * v.z + v.w * v.w;
    for (int o = 32; o; o >>= 1) { s += __shfl_xor(s, o); ss += __shfl_xor(ss, o); }
    __shared__ float red[4];
    if ((t & 63) == 0) { red[t >> 6] = s; red[2 + (t >> 6)] = ss; }
    __syncthreads();
    s = red[0] + red[1]; ss = red[2] + red[3];
    const float mu = s * (1.f / 512.f);
    const float rstd = rsqrtf(ss * (1.f / 512.f) - mu * mu + 1e-5f);
    const float4 gv = reinterpret_cast<const float4*>(g)[t];
    const float4 bv = reinterpret_cast<const float4*>(be)[t];
    const float4 ga = reinterpret_cast<const float4*>(gamma + b * 512)[t];
    const float4 bb = reinterpret_cast<const float4*>(beta + b * 512)[t];
    bf16x4 ov;
    ov[0] = (bf16_t)(((v.x - mu) * rstd * gv.x + bv.x) * (1.f + ga.x) + bb.x);
    ov[1] = (bf16_t)(((v.y - mu) * rstd * gv.y + bv.y) * (1.f + ga.y) + bb.y);
    ov[2] = (bf16_t)(((v.z - mu) * rstd * gv.z + bv.z) * (1.f + ga.z) + bb.z);
    ov[3] = (bf16_t)(((v.w - mu) * rstd * gv.w + bv.w) * (1.f + ga.w) + bb.w);
    reinterpret_cast<bf16x4*>(out + (long long)row * 512)[t] = ov;
}

// ---------------- 128x128x64 bf16 MFMA GEMM, dbuf single-barrier, XCD-swizzled
template <int EPI>
__global__ __launch_bounds__(256) void gemm128_kernel(
    const bf16_t* __restrict__ A, const bf16_t* __restrict__ B,
    const float* __restrict__ bias, void* Cout,
    int M, int N, int K, int lda, int ldb, int ldc)
{
    const int nbx = gridDim.x;
    const int lin = blockIdx.y * nbx + blockIdx.x;
    const int cpx = (nbx * gridDim.y) >> 3;
    const int swz = (lin & 7) * cpx + (lin >> 3);
    const int m0 = (swz / nbx) * 128, n0 = (swz % nbx) * 128;
    const int tid = threadIdx.x, lane = tid & 63, wid = tid >> 6;
    const int wr = wid >> 1, wc = wid & 1;

    __shared__ bf16_t As[16384];
    __shared__ bf16_t Bs[16384];

    f32x4 acc[4][4];
#pragma unroll
    for (int m = 0; m < 4; ++m)
#pragma unroll
        for (int n = 0; n < 4; ++n) acc[m][n] = (f32x4){0.f, 0.f, 0.f, 0.f};

    const int r8 = lane >> 3;
    const int lc = (lane & 7) ^ r8;
    long long aOff[4], bOff[4];
#pragma unroll
    for (int i = 0; i < 4; ++i) {
        const int row = i * 32 + wid * 8 + r8;
        aOff[i] = (long long)(m0 + row) * lda + lc * 8;
        bOff[i] = (long long)(n0 + row) * ldb + lc * 8;
    }

    const int frow = lane & 15, lg = lane >> 4;
    const int p0 = lg ^ (frow & 7);

#pragma unroll
    for (int i = 0; i < 4; ++i) gload_lds16(A + aOff[i], As + i * 2048 + wid * 512);
#pragma unroll
    for (int i = 0; i < 4; ++i) gload_lds16(B + bOff[i], Bs + i * 2048 + wid * 512);

    for (int kt = 0; kt < K; kt += 64) {
        const int cur = (kt >> 6) & 1;
        __syncthreads();
        if (kt + 64 < K) {
            const int nxt = (cur ^ 1) * 8192;
#pragma unroll
            for (int i = 0; i < 4; ++i) gload_lds16(A + aOff[i] + kt + 64, As + nxt + i * 2048 + wid * 512);
#pragma unroll
            for (int i = 0; i < 4; ++i) gload_lds16(B + bOff[i] + kt + 64, Bs + nxt + i * 2048 + wid * 512);
        }
        const bf16_t* Ab = As + cur * 8192;
        const bf16_t* Bb = Bs + cur * 8192;
        __builtin_amdgcn_s_setprio(1);
#pragma unroll
        for (int kk = 0; kk < 2; ++kk) {
            const int pc = p0 ^ (kk << 2);
            bf16x8 af[4], bfv[4];
#pragma unroll
            for (int m = 0; m < 4; ++m)
                af[m] = *reinterpret_cast<const bf16x8*>(Ab + (wr * 64 + m * 16 + frow) * 64 + pc * 8);
#pragma unroll
            for (int n = 0; n < 4; ++n)
                bfv[n] = *reinterpret_cast<const bf16x8*>(Bb + (wc * 64 + n * 16 + frow) * 64 + pc * 8);
#pragma unroll
            for (int m = 0; m < 4; ++m)
#pragma unroll
                for (int n = 0; n < 4; ++n)
                    acc[m][n] = __builtin_amdgcn_mfma_f32_16x16x32_bf16(af[m], bfv[n], acc[m][n], 0, 0, 0);
        }
        __builtin_amdgcn_s_setprio(0);
    }

#pragma unroll
    for (int m = 0; m < 4; ++m) {
        const int gm = m0 + wr * 64 + m * 16 + ((lane >> 4) << 2);
#pragma unroll
        for (int n = 0; n < 4; ++n) {
            const int gn = n0 + wc * 64 + n * 16 + (lane & 15);
            const float bb = bias ? bias[gn] : 0.f;
#pragma unroll
            for (int j = 0; j < 4; ++j) {
                const float v = acc[m][n][j] + bb;
                const int gmj = gm + j;
                if (EPI == 0) {
                    ((bf16_t*)Cout)[(long long)gmj * ldc + gn] = (bf16_t)v;
                } else {
                    ((bf16_t*)Cout)[(long long)gmj * ldc + gn] = (bf16_t)fmaxf(v, 0.f);
                }
            }
        }
    }
}

// ---------------- fused QKV GEMM (dbuf single-barrier, XCD-swizzled)
__global__ __launch_bounds__(256) void gemmqkv_kernel(
    const bf16_t* __restrict__ A, const bf16_t* __restrict__ B,
    const float* __restrict__ bq, const float* __restrict__ bk, const float* __restrict__ bv,
    bf16_t* __restrict__ qkv, bf16_t* __restrict__ vtb)
{
    const int lin = blockIdx.y * 96 + blockIdx.x;
    const int swz = (lin & 7) * 768 + (lin >> 3);
    const int m0 = (swz / 96) * 128, n0 = (swz % 96) * 128;
    const int sec = n0 >> 12;
    const float* bias = (sec == 0) ? bq : ((sec == 1) ? bk : bv);
    const int tid = threadIdx.x, lane = tid & 63, wid = tid >> 6;
    const int wr = wid >> 1, wc = wid & 1;

    __shared__ bf16_t As[16384];
    __shared__ bf16_t Bs[16384];

    f32x4 acc[4][4];
#pragma unroll
    for (int m = 0; m < 4; ++m)
#pragma unroll
        for (int n = 0; n < 4; ++n) acc[m][n] = (f32x4){0.f, 0.f, 0.f, 0.f};

    const int r8 = lane >> 3;
    const int lc = (lane & 7) ^ r8;
    long long aOff[4], bOff[4];
#pragma unroll
    for (int i = 0; i < 4; ++i) {
        const int row = i * 32 + wid * 8 + r8;
        aOff[i] = (long long)(m0 + row) * 512 + lc * 8;
        bOff[i] = (long long)(n0 + row) * 512 + lc * 8;
    }

    const int frow = lane & 15, lg = lane >> 4;
    const int p0 = lg ^ (frow & 7);

#pragma unroll
    for (int i = 0; i < 4; ++i) gload_lds16(A + aOff[i], As + i * 2048 + wid * 512);
#pragma unroll
    for (int i = 0; i < 4; ++i) gload_lds16(B + bOff[i], Bs + i * 2048 + wid * 512);

    for (int kt = 0; kt < 512; kt += 64) {
        const int cur = (kt >> 6) & 1;
        __syncthreads();
        if (kt + 64 < 512) {
            const int nxt = (cur ^ 1) * 8192;
#pragma unroll
            for (int i = 0; i < 4; ++i) gload_lds16(A + aOff[i] + kt + 64, As + nxt + i * 2048 + wid * 512);
#pragma unroll
            for (int i = 0; i < 4; ++i) gload_lds16(B + bOff[i] + kt + 64, Bs + nxt + i * 2048 + wid * 512);
        }
        const bf16_t* Ab = As + cur * 8192;
        const bf16_t* Bb = Bs + cur * 8192;
        __builtin_amdgcn_s_setprio(1);
#pragma unroll
        for (int kk = 0; kk < 2; ++kk) {
            const int pc = p0 ^ (kk << 2);
            bf16x8 af[4], bfv[4];
#pragma unroll
            for (int m = 0; m < 4; ++m)
                af[m] = *reinterpret_cast<const bf16x8*>(Ab + (wr * 64 + m * 16 + frow) * 64 + pc * 8);
#pragma unroll
            for (int n = 0; n < 4; ++n)
                bfv[n] = *reinterpret_cast<const bf16x8*>(Bb + (wc * 64 + n * 16 + frow) * 64 + pc * 8);
#pragma unroll
            for (int m = 0; m < 4; ++m)
#pragma unroll
                for (int n = 0; n < 4; ++n)
                    acc[m][n] = __builtin_amdgcn_mfma_f32_16x16x32_bf16(af[m], bfv[n], acc[m][n], 0, 0, 0);
        }
        __builtin_amdgcn_s_setprio(0);
    }

#pragma unroll
    for (int m = 0; m < 4; ++m) {
        const int gm = m0 + wr * 64 + m * 16 + ((lane >> 4) << 2);
#pragma unroll
        for (int n = 0; n < 4; ++n) {
            const int gn = n0 + wc * 64 + n * 16 + (lane & 15);
            const int gnl = gn & 4095;
            const float bb = bias[gnl];
#pragma unroll
            for (int j = 0; j < 4; ++j) {
                const float v = acc[m][n][j] + bb;
                const int gmj = gm + j;
                if (sec < 2) {
                    qkv[(long long)sec * 33554432 + (long long)gmj * 4096 + gnl] = (bf16_t)v;
                } else {
                    const long long ci =
                        (long long)(((gmj >> 10) * 8 + (gnl >> 9)) * 512 + (gnl & 511)) * 1024 + (gmj & 1023);
                    vtb[ci] = (bf16_t)v;
                }
            }
        }
    }
}

// ---------------- 64x128x64 GEMM (dbuf single-barrier, XCD-swizzled)
__global__ __launch_bounds__(256) void gemm64_kernel(
    const bf16_t* __restrict__ A, const bf16_t* __restrict__ B,
    const float* __restrict__ bias, float* __restrict__ Cout,
    const float* __restrict__ resid, const float* __restrict__ alpha,
    int M, int N, int K, int lda, int ldb)
{
    const int nbx = gridDim.x;
    const int lin = blockIdx.y * nbx + blockIdx.x;
    const int cpx = (nbx * gridDim.y) >> 3;
    const int swz = (lin & 7) * cpx + (lin >> 3);
    const int m0 = (swz / nbx) * 64, n0 = (swz % nbx) * 128;
    const int tid = threadIdx.x, lane = tid & 63, wid = tid >> 6;
    const int wr = wid >> 1, wc = wid & 1;

    __shared__ bf16_t As[8192];
    __shared__ bf16_t Bs[16384];

    f32x4 acc[2][4];
#pragma unroll
    for (int m = 0; m < 2; ++m)
#pragma unroll
        for (int n = 0; n < 4; ++n) acc[m][n] = (f32x4){0.f, 0.f, 0.f, 0.f};

    const int r8 = lane >> 3;
    const int lc = (lane & 7) ^ r8;
    long long aOff[2], bOff[4];
#pragma unroll
    for (int i = 0; i < 2; ++i)
        aOff[i] = (long long)(m0 + i * 32 + wid * 8 + r8) * lda + lc * 8;
#pragma unroll
    for (int i = 0; i < 4; ++i)
        bOff[i] = (long long)(n0 + i * 32 + wid * 8 + r8) * ldb + lc * 8;

    const int frow = lane & 15, lg = lane >> 4;
    const int p0 = lg ^ (frow & 7);

#pragma unroll
    for (int i = 0; i < 2; ++i) gload_lds16(A + aOff[i], As + i * 2048 + wid * 512);
#pragma unroll
    for (int i = 0; i < 4; ++i) gload_lds16(B + bOff[i], Bs + i * 2048 + wid * 512);

    for (int kt = 0; kt < K; kt += 64) {
        const int cur = (kt >> 6) & 1;
        __syncthreads();
        if (kt + 64 < K) {
#pragma unroll
            for (int i = 0; i < 2; ++i)
                gload_lds16(A + aOff[i] + kt + 64, As + (cur ^ 1) * 4096 + i * 2048 + wid * 512);
#pragma unroll
            for (int i = 0; i < 4; ++i)
                gload_lds16(B + bOff[i] + kt + 64, Bs + (cur ^ 1) * 8192 + i * 2048 + wid * 512);
        }
        const bf16_t* Ab = As + cur * 4096;
        const bf16_t* Bb = Bs + cur * 8192;
        __builtin_amdgcn_s_setprio(1);
#pragma unroll
        for (int kk = 0; kk < 2; ++kk) {
            const int pc = p0 ^ (kk << 2);
            bf16x8 af[2], bfv[4];
#pragma unroll
            for (int m = 0; m < 2; ++m)
                af[m] = *reinterpret_cast<const bf16x8*>(Ab + (wr * 32 + m * 16 + frow) * 64 + pc * 8);
#pragma unroll
            for (int n = 0; n < 4; ++n)
                bfv[n] = *reinterpret_cast<const bf16x8*>(Bb + (wc * 64 + n * 16 + frow) * 64 + pc * 8);
#pragma unroll
            for (int m = 0; m < 2; ++m)
#pragma unroll
                for (int n = 0; n < 4; ++n)
                    acc[m][n] = __builtin_amdgcn_mfma_f32_16x16x32_bf16(af[m], bfv[n], acc[m][n], 0, 0, 0);
        }
        __builtin_amdgcn_s_setprio(0);
    }

#pragma unroll
    for (int m = 0; m < 2; ++m) {
        const int gm = m0 + wr * 32 + m * 16 + ((lane >> 4) << 2);
#pragma unroll
        for (int n = 0; n < 4; ++n) {
            const int gn = n0 + wc * 64 + n * 16 + (lane & 15);
            const float bb = bias[gn];
#pragma unroll
            for (int j = 0; j < 4; ++j) {
                const int gmj = gm + j;
                const long long ci = (long long)gmj * 512 + gn;
                Cout[ci] = resid[ci] + (acc[m][n][j] + bb) * alpha[(gmj >> 10) * 512 + gn];
            }
        }
    }
}

// ---------------- fused flash attention v8 = v7 swizzles + K/V time-sharing ONE
// 32KB buffer: LDS 35.8KB -> 4 blocks/CU (4 independent barrier domains cover the
// exposed K/V drains). 4 barriers/iter. Math identical to v6/v7 (verified).
#define FA_LDS 35840
#define SCL 0.04508422132207354f   /* (1/32) * log2(e) */
__global__ __launch_bounds__(256, 4) void flash_kernel(
    bf16_t* __restrict__ qb, const bf16_t* __restrict__ kb, const bf16_t* __restrict__ vtb)
{
    extern __shared__ char smem[];
    bf16_t* KVs = (bf16_t*)smem;              // K: [32][512] chunk16^(row&7) | V: [512][32] chunk16^((e>>1)&3)
    char* PB = smem + 32768;                  // [32 q][32 k]; granule g: chunk (g>>1)^((q>>1)&3), half g&1
    float* pmaxB = (float*)(smem + 34816);    // [32 q][2 wk] pairs
    float* psumB = (float*)(smem + 35328);    // [32 q][2 wk] pairs

    const int bid = blockIdx.x;
    const int xcd = bid & 7, idx = bid >> 3;
    const int qt = idx & 31, bhl = idx >> 5;
    const int bh = xcd * 8 + bhl;
    const int b = bh >> 3, h = bh & 7;
    const int q0 = qt * 32;
    const int tid = threadIdx.x, lane = tid & 63, wid = tid >> 6;  // 4 waves
    const int laneq = lane & 15, lx = lane & 7, lg = lane >> 4;
    const int wk = wid >> 1, wq = wid & 1;    // S role: k-half, q-half
    const int we = wid;                       // PV role: e-quarter

    // ---- prologue: stage K(0); Q frags to registers
#pragma unroll
    for (int r = 0; r < 8; ++r) {
        const int row = r * 4 + wid;
        gload_lds16(kb + ((long long)(b * 1024 + row) * 8 + h) * 512 + ((lane ^ (row & 7)) << 3),
                    KVs + row * 512);
    }
    const int qi = wq * 16 + laneq;
    bf16x8 qfrag[16];
    {
        const bf16_t* qrow = qb + ((long long)(b * 1024 + q0 + qi) * 8 + h) * 512 + lg * 8;
#pragma unroll
        for (int ks = 0; ks < 16; ++ks) qfrag[ks] = *reinterpret_cast<const bf16x8*>(qrow + ks * 32);
    }
    f32x4 accA[8], accB[8];
#pragma unroll
    for (int e = 0; e < 8; ++e) { accA[e] = (f32x4){0.f,0.f,0.f,0.f}; accB[e] = (f32x4){0.f,0.f,0.f,0.f}; }
    float mS = 0.f, mPA = 0.f, mPB = 0.f, lA = 0.f, lB = 0.f;
    const int rA = wk * 16 + laneq;           // K LDS row for S-phase
    const int qA = laneq, qB = laneq + 16;    // PV-role q rows

    for (int t = 0; t < 32; ++t) {
        __syncthreads();  // (D): K(t) landed (compiler drains vmcnt before barrier)
        // (b) S-phase: S^T tile = K · Q^T (16 MFMAs)
        f32x4 s0 = (f32x4){0.f, 0.f, 0.f, 0.f};
        const char* KsB = (const char*)KVs;
        __builtin_amdgcn_s_setprio(1);
#pragma unroll
        for (int ks = 0; ks < 16; ++ks) {
            const int co = (((ks * 4 + lg) ^ lx) << 4);
            bf16x8 a0 = *(const bf16x8*)(KsB + rA * 1024 + co);
            s0 = __builtin_amdgcn_mfma_f32_16x16x32_bf16(a0, qfrag[ks], s0, 0, 0, 0);
        }
        __builtin_amdgcn_s_setprio(0);
        // (c) delayed-max softmax partials (registers only)
        float f[4], pe[4];
#pragma unroll
        for (int j = 0; j < 4; ++j) f[j] = s0[j] * SCL;
        float mloc = fmaxf(fmaxf(f[0], f[1]), fmaxf(f[2], f[3]));
        mloc = fmaxf(mloc, __shfl_xor(mloc, 16));
        mloc = fmaxf(mloc, __shfl_xor(mloc, 32));
        float sl = 0.f;
#pragma unroll
        for (int j = 0; j < 4; ++j) { pe[j] = exp2f(f[j] - mS); sl += pe[j]; }
        sl += __shfl_xor(sl, 16);
        sl += __shfl_xor(sl, 32);
        __syncthreads();  // (A): all K reads done -> buffer free for V
        // (a) stage V(t) into the shared buffer
#pragma unroll
        for (int r = 0; r < 8; ++r) {
            const int e0 = (r * 4 + wid) * 16;
            const int e = e0 + (lane >> 2);
            gload_lds16(vtb + ((long long)bh * 512 + e) * 1024 + t * 32
                            + (((lane & 3) ^ ((e >> 1) & 3)) << 3),
                        KVs + e0 * 32);
        }
        // write P + stats (regions disjoint from KVs)
        if (lane < 16) {
            const int si = (wq * 16 + lane) * 2 + wk;
            pmaxB[si] = mloc;
            psumB[si] = sl;
        }
        {
            bf16x4 p;
#pragma unroll
            for (int j = 0; j < 4; ++j) p[j] = (bf16_t)pe[j];
            const int g = wk * 4 + lg;
            *(bf16x4*)(PB + qi * 64 + ((((g >> 1) ^ ((qi >> 1) & 3))) << 4) + ((g & 1) << 3)) = p;
        }
        __syncthreads();  // (B): V landed + P/stats visible
        // (f) PV: 16 MFMAs
        const char* VB = (const char*)KVs;
        bf16x8 pA = *(const bf16x8*)(PB + qA * 64 + ((lg ^ ((qA >> 1) & 3)) << 4));
        bf16x8 pBv = *(const bf16x8*)(PB + qB * 64 + ((lg ^ ((qB >> 1) & 3)) << 4));
        __builtin_amdgcn_s_setprio(1);
#pragma unroll
        for (int ef = 0; ef < 8; ++ef) {
            const int re = we * 128 + ef * 16 + laneq;
            bf16x8 av = *(const bf16x8*)(VB + re * 64 + ((lg ^ ((re >> 1) & 3)) << 4));
            accA[ef] = __builtin_amdgcn_mfma_f32_16x16x32_bf16(av, pA, accA[ef], 0, 0, 0);
            accB[ef] = __builtin_amdgcn_mfma_f32_16x16x32_bf16(av, pBv, accB[ef], 0, 0, 0);
        }
        __builtin_amdgcn_s_setprio(0);
        // stats: paired reads, accumulate in old-max units, rescale to new max
        {
            const float2 pmA = *(const float2*)&pmaxB[qA * 2];
            const float2 pmB = *(const float2*)&pmaxB[qB * 2];
            const float2 psA = *(const float2*)&psumB[qA * 2];
            const float2 psB = *(const float2*)&psumB[qB * 2];
            mS = fmaxf(mS, wq ? fmaxf(pmB.x, pmB.y) : fmaxf(pmA.x, pmA.y));
            lA += psA.x + psA.y;
            lB += psB.x + psB.y;
            const float mnA = fmaxf(mPA, fmaxf(pmA.x, pmA.y));
            const float mnB = fmaxf(mPB, fmaxf(pmB.x, pmB.y));
            if (__ballot((mnA > mPA) || (mnB > mPB))) {
                const float rsA = exp2f(mPA - mnA), rsB = exp2f(mPB - mnB);
                lA *= rsA; lB *= rsB;
#pragma unroll
                for (int e = 0; e < 8; ++e) {
#pragma unroll
                    for (int j = 0; j < 4; ++j) { accA[e][j] *= rsA; accB[e][j] *= rsB; }
                }
            }
            mPA = mnA; mPB = mnB;
        }
        __syncthreads();  // (C): V/P/stat reads done -> buffer free for K(t+1)
        // (e) stage K(t+1)
        if (t < 31) {
#pragma unroll
            for (int r = 0; r < 8; ++r) {
                const int row = r * 4 + wid;
                gload_lds16(kb + ((long long)(b * 1024 + t * 32 + 32 + row) * 8 + h) * 512
                                + ((lane ^ (row & 7)) << 3),
                            KVs + row * 512);
            }
        }
    }

    // ---- epilogue: O = acc / l, store over qb
    const float iA = 1.f / lA, iB = 1.f / lB;
#pragma unroll
    for (int ef = 0; ef < 8; ++ef) {
        const int e0 = we * 128 + ef * 16 + lg * 4;
        bf16x4 oA, oB;
#pragma unroll
        for (int j = 0; j < 4; ++j) { oA[j] = (bf16_t)(accA[ef][j] * iA); oB[j] = (bf16_t)(accB[ef][j] * iB); }
        *(bf16x4*)(qb + ((long long)(b * 1024 + q0 + qA) * 8 + h) * 512 + e0) = oA;
        *(bf16x4*)(qb + ((long long)(b * 1024 + q0 + qB) * 8 + h) * 512 + e0) = oB;
    }
}

extern "C" void kernel_launch(void* const* d_in, const int* in_sizes, int n_in,
                              void* d_out, int out_size, void* d_ws, size_t ws_size,
                              hipStream_t stream)
{
    const float* x    = (const float*)d_in[0];
    const float* cond = (const float*)d_in[1];
    const float* g1w  = (const float*)d_in[2];  const float* g1b  = (const float*)d_in[3];
    const float* be1w = (const float*)d_in[4];  const float* be1b = (const float*)d_in[5];
    const float* a1w  = (const float*)d_in[6];  const float* a1b  = (const float*)d_in[7];
    const float* g2w  = (const float*)d_in[8];  const float* g2b  = (const float*)d_in[9];
    const float* be2w = (const float*)d_in[10]; const float* be2b = (const float*)d_in[11];
    const float* a2w  = (const float*)d_in[12]; const float* a2b  = (const float*)d_in[13];
    const float* ln1g = (const float*)d_in[14]; const float* ln1b = (const float*)d_in[15];
    const float* ln2g = (const float*)d_in[16]; const float* ln2b = (const float*)d_in[17];
    const float* wq   = (const float*)d_in[18]; const float* bq   = (const float*)d_in[19];
    const float* wk   = (const float*)d_in[20]; const float* bk   = (const float*)d_in[21];
    const float* wv   = (const float*)d_in[22]; const float* bv   = (const float*)d_in[23];
    const float* lvw  = (const float*)d_in[24]; const float* lvb  = (const float*)d_in[25];
    const float* f1w  = (const float*)d_in[26]; const float* f1b  = (const float*)d_in[27];
    const float* f2w  = (const float*)d_in[28]; const float* f2b  = (const float*)d_in[29];
    (void)in_sizes; (void)n_in; (void)out_size; (void)ws_size;

    // workspace layout (bytes)
    char* w8 = (char*)d_ws;
    float*  mod  = (float*)(w8);                                   //  98304
    bf16_t* wqT  = (bf16_t*)(w8 + 98304);                          // 4096x512 bf16 (wq/wk/wv contiguous)
    bf16_t* lvwT = (bf16_t*)(w8 + 98304 + 3 * 4194304);            // 512x4096
    bf16_t* f1wT = (bf16_t*)(w8 + 98304 + 4 * 4194304);            // 2048x512
    bf16_t* f2wT = (bf16_t*)(w8 + 98304 + 4 * 4194304 + 2097152);  // 512x2048
    bf16_t* ybf  = (bf16_t*)(w8 + 98304 + 4 * 4194304 + 2 * 2097152);           // 8192x512
    bf16_t* qb   = (bf16_t*)(w8 + 98304 + 4 * 4194304 + 2 * 2097152 + 8388608); // (b,s,h,e); O in place
    bf16_t* kb   = qb + 33554432;    // (b,s,h,e)
    bf16_t* vtb  = kb + 33554432;    // V transposed: (b,h,e,s)

    (void)hipFuncSetAttribute((const void*)flash_kernel,
                              hipFuncAttributeMaxDynamicSharedMemorySize, FA_LDS);

    const dim3 blk(256);
    // weight transposes + modulation signals in one launch
    prep_kernel<<<10288, blk, 0, stream>>>(wq, wk, wv, lvw, f1w, f2w,
                                           wqT, lvwT, f1wT, f2wT,
                                           cond, g1w, be1w, a1w, g2w, be2w, a2w,
                                           g1b, be1b, a1b, g2b, be2b, a2b, mod);
    // LN1 + modulate -> y (bf16)
    ln_mod_kernel<<<8192, 128, 0, stream>>>(x, ln1g, ln1b, mod, mod + 4096, ybf);
    // fused QKV projection (V stored transposed)
    gemmqkv_kernel<<<dim3(96, 64), blk, 0, stream>>>(ybf, wqT, bq, bk, bv, qb, vtb);
    // fused flash attention: O overwrites qb
    flash_kernel<<<2048, 256, FA_LDS, stream>>>(qb, kb, vtb);
    // y2 = x + (O @ lvw + lvb) * alpha1 -> d_out (fp32)
    gemm64_kernel<<<dim3(4, 128), blk, 0, stream>>>(qb, lvwT, lvb, (float*)d_out, x, mod + 8192,
        8192, 512, 4096, 4096, 4096);
    // LN2 + modulate -> z (bf16)
    ln_mod_kernel<<<8192, 128, 0, stream>>>((const float*)d_out, ln2g, ln2b,
                                            mod + 12288, mod + 16384, ybf);
    // FFN
    gemm128_kernel<1><<<dim3(16, 64), blk, 0, stream>>>(ybf, f1wT, f1b, qb,
        8192, 2048, 512, 512, 512, 2048);
    gemm64_kernel<<<dim3(4, 128), blk, 0, stream>>>(qb, f2wT, f2b, (float*)d_out,
        (const float*)d_out, mod + 20480,
        8192, 512, 2048, 2048, 2048);
}

// Round 13
// 733.078 us; speedup vs baseline: 2.3159x; 2.3159x over previous
//
#include <hip/hip_runtime.h>
#include <hip/hip_bf16.h>

typedef __bf16 bf16_t;
typedef bf16_t bf16x8 __attribute__((ext_vector_type(8)));
typedef bf16_t bf16x4 __attribute__((ext_vector_type(4)));
typedef float f32x4 __attribute__((ext_vector_type(4)));

typedef const __attribute__((address_space(1))) void GV;
typedef __attribute__((address_space(3))) void LV;

__device__ __forceinline__ void gload_lds16(const bf16_t* gsrc, bf16_t* ldst) {
    __builtin_amdgcn_global_load_lds((GV*)gsrc, (LV*)ldst, 16, 0, 0);
}

// ---------------- prep: 6 weight transposes (bid<10240) + 6 modsig linears (bid>=10240)
__global__ __launch_bounds__(256) void prep_kernel(
    const float* __restrict__ wq, const float* __restrict__ wk, const float* __restrict__ wv,
    const float* __restrict__ lvw, const float* __restrict__ f1w, const float* __restrict__ f2w,
    bf16_t* __restrict__ wqT, bf16_t* __restrict__ lvwT,
    bf16_t* __restrict__ f1wT, bf16_t* __restrict__ f2wT,
    const float* __restrict__ cond,
    const float* __restrict__ mw0, const float* __restrict__ mw1, const float* __restrict__ mw2,
    const float* __restrict__ mw3, const float* __restrict__ mw4, const float* __restrict__ mw5,
    const float* __restrict__ mc0, const float* __restrict__ mc1, const float* __restrict__ mc2,
    const float* __restrict__ mc3, const float* __restrict__ mc4, const float* __restrict__ mc5,
    float* __restrict__ mod)
{
    __shared__ float sbuf[32 * 33];
    const int bid = blockIdx.x;
    if (bid < 10240) {
        float (*tile)[33] = (float(*)[33])sbuf;
        const float* in; bf16_t* out; int N, nx, K, local;
        if (bid < 6144) {
            const int sec = bid >> 11;
            local = bid & 2047;
            in = (sec == 0) ? wq : ((sec == 1) ? wk : wv);
            out = wqT + (long long)sec * 2097152;
            K = 512; N = 4096; nx = 128;
        } else if (bid < 8192) {
            local = bid - 6144; in = lvw; out = lvwT; K = 4096; N = 512; nx = 16;
        } else if (bid < 9216) {
            local = bid - 8192; in = f1w; out = f1wT; K = 512; N = 2048; nx = 64;
        } else {
            local = bid - 9216; in = f2w; out = f2wT; K = 2048; N = 512; nx = 16;
        }
        const int n0 = (local % nx) * 32, k0 = (local / nx) * 32;
        const int tx = threadIdx.x & 31, ty = threadIdx.x >> 5;
#pragma unroll
        for (int i = 0; i < 32; i += 8)
            tile[ty + i][tx] = in[(long long)(k0 + ty + i) * N + n0 + tx];
        __syncthreads();
#pragma unroll
        for (int i = 0; i < 32; i += 8)
            out[(long long)(n0 + ty + i) * K + k0 + tx] = (bf16_t)tile[tx][ty + i];
    } else {
        float* cs = sbuf;
        const int lb = bid - 10240;
        const int sig = lb >> 3, b = lb & 7;
        const float* w; const float* bi;
        switch (sig) {
            case 0: w = mw0; bi = mc0; break;
            case 1: w = mw1; bi = mc1; break;
            case 2: w = mw2; bi = mc2; break;
            case 3: w = mw3; bi = mc3; break;
            case 4: w = mw4; bi = mc4; break;
            default: w = mw5; bi = mc5; break;
        }
        for (int i = threadIdx.x; i < 512; i += 256) cs[i] = cond[b * 512 + i];
        __syncthreads();
        for (int n = threadIdx.x; n < 512; n += 256) {
            float s0 = 0.f, s1 = 0.f, s2 = 0.f, s3 = 0.f;
            for (int i = 0; i < 512; i += 4) {
                s0 = fmaf(cs[i], w[(long long)i * 512 + n], s0);
                s1 = fmaf(cs[i + 1], w[(long long)(i + 1) * 512 + n], s1);
                s2 = fmaf(cs[i + 2], w[(long long)(i + 2) * 512 + n], s2);
                s3 = fmaf(cs[i + 3], w[(long long)(i + 3) * 512 + n], s3);
            }
            mod[(long long)(sig * 8 + b) * 512 + n] = bi[n] + (s0 + s1) + (s2 + s3);
        }
    }
}

// ---------------- fused LayerNorm + AdaLN modulate, fp32 -> bf16
__global__ __launch_bounds__(128) void ln_mod_kernel(
    const float* __restrict__ x, const float* __restrict__ g, const float* __restrict__ be,
    const float* __restrict__ gamma, const float* __restrict__ beta, bf16_t* __restrict__ out)
{
    const int row = blockIdx.x;
    const int b = row >> 10;
    const int t = threadIdx.x;
    const float4 v = reinterpret_cast<const float4*>(x + (long long)row * 512)[t];
    float s = v.x + v.y + v.z + v.w;
    float ss = v.x * v.x + v.y * v.y + v.z * v.z + v.w * v.w;
    for (int o = 32; o; o >>= 1) { s += __shfl_xor(s, o); ss += __shfl_xor(ss, o); }
    __shared__ float red[4];
    if ((t & 63) == 0) { red[t >> 6] = s; red[2 + (t >> 6)] = ss; }
    __syncthreads();
    s = red[0] + red[1]; ss = red[2] + red[3];
    const float mu = s * (1.f / 512.f);
    const float rstd = rsqrtf(ss * (1.f / 512.f) - mu * mu + 1e-5f);
    const float4 gv = reinterpret_cast<const float4*>(g)[t];
    const float4 bv = reinterpret_cast<const float4*>(be)[t];
    const float4 ga = reinterpret_cast<const float4*>(gamma + b * 512)[t];
    const float4 bb = reinterpret_cast<const float4*>(beta + b * 512)[t];
    bf16x4 ov;
    ov[0] = (bf16_t)(((v.x - mu) * rstd * gv.x + bv.x) * (1.f + ga.x) + bb.x);
    ov[1] = (bf16_t)(((v.y - mu) * rstd * gv.y + bv.y) * (1.f + ga.y) + bb.y);
    ov[2] = (bf16_t)(((v.z - mu) * rstd * gv.z + bv.z) * (1.f + ga.z) + bb.z);
    ov[3] = (bf16_t)(((v.w - mu) * rstd * gv.w + bv.w) * (1.f + ga.w) + bb.w);
    reinterpret_cast<bf16x4*>(out + (long long)row * 512)[t] = ov;
}

// ---------------- 128x128x64 bf16 MFMA GEMM, dbuf single-barrier, XCD-swizzled
template <int EPI>
__global__ __launch_bounds__(256) void gemm128_kernel(
    const bf16_t* __restrict__ A, const bf16_t* __restrict__ B,
    const float* __restrict__ bias, void* Cout,
    int M, int N, int K, int lda, int ldb, int ldc)
{
    const int nbx = gridDim.x;
    const int lin = blockIdx.y * nbx + blockIdx.x;
    const int cpx = (nbx * gridDim.y) >> 3;
    const int swz = (lin & 7) * cpx + (lin >> 3);
    const int m0 = (swz / nbx) * 128, n0 = (swz % nbx) * 128;
    const int tid = threadIdx.x, lane = tid & 63, wid = tid >> 6;
    const int wr = wid >> 1, wc = wid & 1;

    __shared__ bf16_t As[16384];
    __shared__ bf16_t Bs[16384];

    f32x4 acc[4][4];
#pragma unroll
    for (int m = 0; m < 4; ++m)
#pragma unroll
        for (int n = 0; n < 4; ++n) acc[m][n] = (f32x4){0.f, 0.f, 0.f, 0.f};

    const int r8 = lane >> 3;
    const int lc = (lane & 7) ^ r8;
    long long aOff[4], bOff[4];
#pragma unroll
    for (int i = 0; i < 4; ++i) {
        const int row = i * 32 + wid * 8 + r8;
        aOff[i] = (long long)(m0 + row) * lda + lc * 8;
        bOff[i] = (long long)(n0 + row) * ldb + lc * 8;
    }

    const int frow = lane & 15, lg = lane >> 4;
    const int p0 = lg ^ (frow & 7);

#pragma unroll
    for (int i = 0; i < 4; ++i) gload_lds16(A + aOff[i], As + i * 2048 + wid * 512);
#pragma unroll
    for (int i = 0; i < 4; ++i) gload_lds16(B + bOff[i], Bs + i * 2048 + wid * 512);

    for (int kt = 0; kt < K; kt += 64) {
        const int cur = (kt >> 6) & 1;
        __syncthreads();
        if (kt + 64 < K) {
            const int nxt = (cur ^ 1) * 8192;
#pragma unroll
            for (int i = 0; i < 4; ++i) gload_lds16(A + aOff[i] + kt + 64, As + nxt + i * 2048 + wid * 512);
#pragma unroll
            for (int i = 0; i < 4; ++i) gload_lds16(B + bOff[i] + kt + 64, Bs + nxt + i * 2048 + wid * 512);
        }
        const bf16_t* Ab = As + cur * 8192;
        const bf16_t* Bb = Bs + cur * 8192;
        __builtin_amdgcn_s_setprio(1);
#pragma unroll
        for (int kk = 0; kk < 2; ++kk) {
            const int pc = p0 ^ (kk << 2);
            bf16x8 af[4], bfv[4];
#pragma unroll
            for (int m = 0; m < 4; ++m)
                af[m] = *reinterpret_cast<const bf16x8*>(Ab + (wr * 64 + m * 16 + frow) * 64 + pc * 8);
#pragma unroll
            for (int n = 0; n < 4; ++n)
                bfv[n] = *reinterpret_cast<const bf16x8*>(Bb + (wc * 64 + n * 16 + frow) * 64 + pc * 8);
#pragma unroll
            for (int m = 0; m < 4; ++m)
#pragma unroll
                for (int n = 0; n < 4; ++n)
                    acc[m][n] = __builtin_amdgcn_mfma_f32_16x16x32_bf16(af[m], bfv[n], acc[m][n], 0, 0, 0);
        }
        __builtin_amdgcn_s_setprio(0);
    }

#pragma unroll
    for (int m = 0; m < 4; ++m) {
        const int gm = m0 + wr * 64 + m * 16 + ((lane >> 4) << 2);
#pragma unroll
        for (int n = 0; n < 4; ++n) {
            const int gn = n0 + wc * 64 + n * 16 + (lane & 15);
            const float bb = bias ? bias[gn] : 0.f;
#pragma unroll
            for (int j = 0; j < 4; ++j) {
                const float v = acc[m][n][j] + bb;
                const int gmj = gm + j;
                if (EPI == 0) {
                    ((bf16_t*)Cout)[(long long)gmj * ldc + gn] = (bf16_t)v;
                } else {
                    ((bf16_t*)Cout)[(long long)gmj * ldc + gn] = (bf16_t)fmaxf(v, 0.f);
                }
            }
        }
    }
}

// ---------------- fused QKV GEMM: 256x128 tile, single-buffer, XCD-swizzled
// B = [wqT;wkT;wvT] (12288 x 512); n-section 0 -> qb, 1 -> kb, 2 -> vtb
__global__ __launch_bounds__(256) void gemmqkv_kernel(
    const bf16_t* __restrict__ A, const bf16_t* __restrict__ B,
    const float* __restrict__ bq, const float* __restrict__ bk, const float* __restrict__ bv,
    bf16_t* __restrict__ qkv, bf16_t* __restrict__ vtb)
{
    const int lin = blockIdx.y * 96 + blockIdx.x;     // grid (96, 32)
    const int swz = (lin & 7) * 384 + (lin >> 3);
    const int m0 = (swz / 96) * 256, n0 = (swz % 96) * 128;
    const int sec = n0 >> 12;
    const float* bias = (sec == 0) ? bq : ((sec == 1) ? bk : bv);
    const int tid = threadIdx.x, lane = tid & 63, wid = tid >> 6;
    const int wr = wid >> 1, wc = wid & 1;            // wave owns 128m x 64n

    __shared__ bf16_t As[16384];   // 256 x 64
    __shared__ bf16_t Bs[8192];    // 128 x 64

    f32x4 acc[8][4];
#pragma unroll
    for (int m = 0; m < 8; ++m)
#pragma unroll
        for (int n = 0; n < 4; ++n) acc[m][n] = (f32x4){0.f, 0.f, 0.f, 0.f};

    const int r8 = lane >> 3;
    const int lc = (lane & 7) ^ r8;
    long long aOff[8], bOff[4];
#pragma unroll
    for (int i = 0; i < 8; ++i)
        aOff[i] = (long long)(m0 + i * 32 + wid * 8 + r8) * 512 + lc * 8;
#pragma unroll
    for (int i = 0; i < 4; ++i)
        bOff[i] = (long long)(n0 + i * 32 + wid * 8 + r8) * 512 + lc * 8;

    const int frow = lane & 15, lg = lane >> 4;
    const int p0 = lg ^ (frow & 7);

    for (int kt = 0; kt < 512; kt += 64) {
#pragma unroll
        for (int i = 0; i < 8; ++i) gload_lds16(A + aOff[i] + kt, As + i * 2048 + wid * 512);
#pragma unroll
        for (int i = 0; i < 4; ++i) gload_lds16(B + bOff[i] + kt, Bs + i * 2048 + wid * 512);
        __syncthreads();
        __builtin_amdgcn_s_setprio(1);
#pragma unroll
        for (int kk = 0; kk < 2; ++kk) {
            const int pc = p0 ^ (kk << 2);
            bf16x8 bfv[4];
#pragma unroll
            for (int n = 0; n < 4; ++n)
                bfv[n] = *reinterpret_cast<const bf16x8*>(Bs + (wc * 64 + n * 16 + frow) * 64 + pc * 8);
#pragma unroll
            for (int m = 0; m < 8; ++m) {
                const bf16x8 af = *reinterpret_cast<const bf16x8*>(As + (wr * 128 + m * 16 + frow) * 64 + pc * 8);
#pragma unroll
                for (int n = 0; n < 4; ++n)
                    acc[m][n] = __builtin_amdgcn_mfma_f32_16x16x32_bf16(af, bfv[n], acc[m][n], 0, 0, 0);
            }
        }
        __builtin_amdgcn_s_setprio(0);
        __syncthreads();
    }

#pragma unroll
    for (int m = 0; m < 8; ++m) {
        const int gm = m0 + wr * 128 + m * 16 + ((lane >> 4) << 2);
#pragma unroll
        for (int n = 0; n < 4; ++n) {
            const int gn = n0 + wc * 64 + n * 16 + (lane & 15);
            const int gnl = gn & 4095;
            const float bb = bias[gnl];
#pragma unroll
            for (int j = 0; j < 4; ++j) {
                const float v = acc[m][n][j] + bb;
                const int gmj = gm + j;
                if (sec < 2) {
                    qkv[(long long)sec * 33554432 + (long long)gmj * 4096 + gnl] = (bf16_t)v;
                } else {
                    const long long ci =
                        (long long)(((gmj >> 10) * 8 + (gnl >> 9)) * 512 + (gnl & 511)) * 1024 + (gmj & 1023);
                    vtb[ci] = (bf16_t)v;
                }
            }
        }
    }
}

// ---------------- 64x128x64 GEMM (dbuf single-barrier, XCD-swizzled)
__global__ __launch_bounds__(256) void gemm64_kernel(
    const bf16_t* __restrict__ A, const bf16_t* __restrict__ B,
    const float* __restrict__ bias, float* __restrict__ Cout,
    const float* __restrict__ resid, const float* __restrict__ alpha,
    int M, int N, int K, int lda, int ldb)
{
    const int nbx = gridDim.x;
    const int lin = blockIdx.y * nbx + blockIdx.x;
    const int cpx = (nbx * gridDim.y) >> 3;
    const int swz = (lin & 7) * cpx + (lin >> 3);
    const int m0 = (swz / nbx) * 64, n0 = (swz % nbx) * 128;
    const int tid = threadIdx.x, lane = tid & 63, wid = tid >> 6;
    const int wr = wid >> 1, wc = wid & 1;

    __shared__ bf16_t As[8192];
    __shared__ bf16_t Bs[16384];

    f32x4 acc[2][4];
#pragma unroll
    for (int m = 0; m < 2; ++m)
#pragma unroll
        for (int n = 0; n < 4; ++n) acc[m][n] = (f32x4){0.f, 0.f, 0.f, 0.f};

    const int r8 = lane >> 3;
    const int lc = (lane & 7) ^ r8;
    long long aOff[2], bOff[4];
#pragma unroll
    for (int i = 0; i < 2; ++i)
        aOff[i] = (long long)(m0 + i * 32 + wid * 8 + r8) * lda + lc * 8;
#pragma unroll
    for (int i = 0; i < 4; ++i)
        bOff[i] = (long long)(n0 + i * 32 + wid * 8 + r8) * ldb + lc * 8;

    const int frow = lane & 15, lg = lane >> 4;
    const int p0 = lg ^ (frow & 7);

#pragma unroll
    for (int i = 0; i < 2; ++i) gload_lds16(A + aOff[i], As + i * 2048 + wid * 512);
#pragma unroll
    for (int i = 0; i < 4; ++i) gload_lds16(B + bOff[i], Bs + i * 2048 + wid * 512);

    for (int kt = 0; kt < K; kt += 64) {
        const int cur = (kt >> 6) & 1;
        __syncthreads();
        if (kt + 64 < K) {
#pragma unroll
            for (int i = 0; i < 2; ++i)
                gload_lds16(A + aOff[i] + kt + 64, As + (cur ^ 1) * 4096 + i * 2048 + wid * 512);
#pragma unroll
            for (int i = 0; i < 4; ++i)
                gload_lds16(B + bOff[i] + kt + 64, Bs + (cur ^ 1) * 8192 + i * 2048 + wid * 512);
        }
        const bf16_t* Ab = As + cur * 4096;
        const bf16_t* Bb = Bs + cur * 8192;
        __builtin_amdgcn_s_setprio(1);
#pragma unroll
        for (int kk = 0; kk < 2; ++kk) {
            const int pc = p0 ^ (kk << 2);
            bf16x8 af[2], bfv[4];
#pragma unroll
            for (int m = 0; m < 2; ++m)
                af[m] = *reinterpret_cast<const bf16x8*>(Ab + (wr * 32 + m * 16 + frow) * 64 + pc * 8);
#pragma unroll
            for (int n = 0; n < 4; ++n)
                bfv[n] = *reinterpret_cast<const bf16x8*>(Bb + (wc * 64 + n * 16 + frow) * 64 + pc * 8);
#pragma unroll
            for (int m = 0; m < 2; ++m)
#pragma unroll
                for (int n = 0; n < 4; ++n)
                    acc[m][n] = __builtin_amdgcn_mfma_f32_16x16x32_bf16(af[m], bfv[n], acc[m][n], 0, 0, 0);
        }
        __builtin_amdgcn_s_setprio(0);
    }

#pragma unroll
    for (int m = 0; m < 2; ++m) {
        const int gm = m0 + wr * 32 + m * 16 + ((lane >> 4) << 2);
#pragma unroll
        for (int n = 0; n < 4; ++n) {
            const int gn = n0 + wc * 64 + n * 16 + (lane & 15);
            const float bb = bias[gn];
#pragma unroll
            for (int j = 0; j < 4; ++j) {
                const int gmj = gm + j;
                const long long ci = (long long)gmj * 512 + gn;
                Cout[ci] = resid[ci] + (acc[m][n][j] + bb) * alpha[(gmj >> 10) * 512 + gn];
            }
        }
    }
}

// ---------------- fused flash attention v9 = round-11 v7 + 4-way split S-accumulator
// (breaks the 16-deep dependent MFMA chain in the S-phase into 4 chains of 4)
#define FA_LDS 69632
#define SCL 0.04508422132207354f   /* (1/32) * log2(e) */
__global__ __launch_bounds__(256, 2) void flash_kernel(
    bf16_t* __restrict__ qb, const bf16_t* __restrict__ kb, const bf16_t* __restrict__ vtb)
{
    extern __shared__ char smem[];
    bf16_t* Ks = (bf16_t*)smem;               // [32][512], chunk16 ^ (row&7)
    bf16_t* Vs = (bf16_t*)(smem + 32768);     // [512][32], chunk16 ^ ((e>>1)&3)
    char* PB = smem + 65536;                  // [32 q][32 k]; granule g: chunk (g>>1)^((q>>1)&3), half g&1
    float* pmaxB = (float*)(smem + 67584);    // [2][32 q][2 wk]
    float* psumB = (float*)(smem + 68608);    // [2][32 q][2 wk]

    const int bid = blockIdx.x;
    const int xcd = bid & 7, idx = bid >> 3;
    const int qt = idx & 31, bhl = idx >> 5;
    const int bh = xcd * 8 + bhl;
    const int b = bh >> 3, h = bh & 7;
    const int q0 = qt * 32;
    const int tid = threadIdx.x, lane = tid & 63, wid = tid >> 6;  // 4 waves
    const int laneq = lane & 15, lx = lane & 7, lg = lane >> 4;
    const int wk = wid >> 1, wq = wid & 1;    // S role: k-half, q-half
    const int we = wid;                       // PV role: e-quarter

    // ---- prologue: stage K(0); Q frags to registers
#pragma unroll
    for (int r = 0; r < 8; ++r) {
        const int row = r * 4 + wid;
        gload_lds16(kb + ((long long)(b * 1024 + row) * 8 + h) * 512 + ((lane ^ (row & 7)) << 3),
                    Ks + row * 512);
    }
    const int qi = wq * 16 + laneq;
    bf16x8 qfrag[16];
    {
        const bf16_t* qrow = qb + ((long long)(b * 1024 + q0 + qi) * 8 + h) * 512 + lg * 8;
#pragma unroll
        for (int ks = 0; ks < 16; ++ks) qfrag[ks] = *reinterpret_cast<const bf16x8*>(qrow + ks * 32);
    }
    f32x4 accA[8], accB[8];
#pragma unroll
    for (int e = 0; e < 8; ++e) { accA[e] = (f32x4){0.f,0.f,0.f,0.f}; accB[e] = (f32x4){0.f,0.f,0.f,0.f}; }
    float mS = 0.f, mPA = 0.f, mPB = 0.f, lA = 0.f, lB = 0.f;
    const int rA = wk * 16 + laneq;           // K LDS row for S-phase
    const int qA = laneq, qB = laneq + 16;    // PV-role q rows
    __syncthreads();

    for (int t = 0; t < 32; ++t) {
        // (a) issue V(t) staging — hidden under S-phase
#pragma unroll
        for (int r = 0; r < 8; ++r) {
            const int e0 = (r * 4 + wid) * 16;
            const int e = e0 + (lane >> 2);
            gload_lds16(vtb + ((long long)bh * 512 + e) * 1024 + t * 32
                            + (((lane & 3) ^ ((e >> 1) & 3)) << 3),
                        Vs + e0 * 32);
        }
        // (b) S-phase: S^T tile = K · Q^T — 16 MFMAs in 4 independent chains
        f32x4 sacc[4];
#pragma unroll
        for (int c = 0; c < 4; ++c) sacc[c] = (f32x4){0.f, 0.f, 0.f, 0.f};
        const char* KsB = (const char*)Ks;
        __builtin_amdgcn_s_setprio(1);
#pragma unroll
        for (int ks = 0; ks < 16; ++ks) {
            const int co = (((ks * 4 + lg) ^ lx) << 4);
            bf16x8 a0 = *(const bf16x8*)(KsB + rA * 1024 + co);
            sacc[ks & 3] = __builtin_amdgcn_mfma_f32_16x16x32_bf16(a0, qfrag[ks], sacc[ks & 3], 0, 0, 0);
        }
        __builtin_amdgcn_s_setprio(0);
        const f32x4 s0 = (sacc[0] + sacc[1]) + (sacc[2] + sacc[3]);
        // (c) delayed-max softmax partials + P write
        float f[4], pe[4];
#pragma unroll
        for (int j = 0; j < 4; ++j) f[j] = s0[j] * SCL;
        float mloc = fmaxf(fmaxf(f[0], f[1]), fmaxf(f[2], f[3]));
        mloc = fmaxf(mloc, __shfl_xor(mloc, 16));
        mloc = fmaxf(mloc, __shfl_xor(mloc, 32));
        float sl = 0.f;
#pragma unroll
        for (int j = 0; j < 4; ++j) { pe[j] = exp2f(f[j] - mS); sl += pe[j]; }
        sl += __shfl_xor(sl, 16);
        sl += __shfl_xor(sl, 32);
        if (lane < 16) {
            const int si = (t & 1) * 64 + (wq * 16 + lane) * 2 + wk;
            pmaxB[si] = mloc;
            psumB[si] = sl;
        }
        {
            bf16x4 p;
#pragma unroll
            for (int j = 0; j < 4; ++j) p[j] = (bf16_t)pe[j];
            const int g = wk * 4 + lg;
            *(bf16x4*)(PB + qi * 64 + ((((g >> 1) ^ ((qi >> 1) & 3))) << 4) + ((g & 1) << 3)) = p;
        }
        __syncthreads();  // (d): V(t)+P+stats ready (vmcnt drained)

        // (e) issue K(t+1) staging — hidden under PV-phase
        if (t < 31) {
#pragma unroll
            for (int r = 0; r < 8; ++r) {
                const int row = r * 4 + wid;
                gload_lds16(kb + ((long long)(b * 1024 + t * 32 + 32 + row) * 8 + h) * 512
                                + ((lane ^ (row & 7)) << 3),
                            Ks + row * 512);
            }
        }
        // (f) PV: 16 MFMAs (K=32 in one MFMA per e-tile)
        const char* VB = (const char*)Vs;
        bf16x8 pA = *(const bf16x8*)(PB + qA * 64 + ((lg ^ ((qA >> 1) & 3)) << 4));
        bf16x8 pBv = *(const bf16x8*)(PB + qB * 64 + ((lg ^ ((qB >> 1) & 3)) << 4));
        __builtin_amdgcn_s_setprio(1);
#pragma unroll
        for (int ef = 0; ef < 8; ++ef) {
            const int re = we * 128 + ef * 16 + laneq;
            bf16x8 av = *(const bf16x8*)(VB + re * 64 + ((lg ^ ((re >> 1) & 3)) << 4));
            accA[ef] = __builtin_amdgcn_mfma_f32_16x16x32_bf16(av, pA, accA[ef], 0, 0, 0);
            accB[ef] = __builtin_amdgcn_mfma_f32_16x16x32_bf16(av, pBv, accB[ef], 0, 0, 0);
        }
        __builtin_amdgcn_s_setprio(0);
        // stats: paired reads, accumulate in old-max units, then rescale to new max
        {
            const float* pmax_t = pmaxB + (t & 1) * 64;
            const float* psum_t = psumB + (t & 1) * 64;
            const float2 pmA = *(const float2*)&pmax_t[qA * 2];
            const float2 pmB = *(const float2*)&pmax_t[qB * 2];
            const float2 psA = *(const float2*)&psum_t[qA * 2];
            const float2 psB = *(const float2*)&psum_t[qB * 2];
            mS = fmaxf(mS, wq ? fmaxf(pmB.x, pmB.y) : fmaxf(pmA.x, pmA.y));
            lA += psA.x + psA.y;
            lB += psB.x + psB.y;
            const float mnA = fmaxf(mPA, fmaxf(pmA.x, pmA.y));
            const float mnB = fmaxf(mPB, fmaxf(pmB.x, pmB.y));
            if (__ballot((mnA > mPA) || (mnB > mPB))) {
                const float rsA = exp2f(mPA - mnA), rsB = exp2f(mPB - mnB);
                lA *= rsA; lB *= rsB;
#pragma unroll
                for (int e = 0; e < 8; ++e) {
#pragma unroll
                    for (int j = 0; j < 4; ++j) { accA[e][j] *= rsA; accB[e][j] *= rsB; }
                }
            }
            mPA = mnA; mPB = mnB;
        }
        __syncthreads();  // (g): K(t+1) ready; P/V reads done
    }

    // ---- epilogue: O = acc / l, store over qb
    const float iA = 1.f / lA, iB = 1.f / lB;
#pragma unroll
    for (int ef = 0; ef < 8; ++ef) {
        const int e0 = we * 128 + ef * 16 + lg * 4;
        bf16x4 oA, oB;
#pragma unroll
        for (int j = 0; j < 4; ++j) { oA[j] = (bf16_t)(accA[ef][j] * iA); oB[j] = (bf16_t)(accB[ef][j] * iB); }
        *(bf16x4*)(qb + ((long long)(b * 1024 + q0 + qA) * 8 + h) * 512 + e0) = oA;
        *(bf16x4*)(qb + ((long long)(b * 1024 + q0 + qB) * 8 + h) * 512 + e0) = oB;
    }
}

extern "C" void kernel_launch(void* const* d_in, const int* in_sizes, int n_in,
                              void* d_out, int out_size, void* d_ws, size_t ws_size,
                              hipStream_t stream)
{
    const float* x    = (const float*)d_in[0];
    const float* cond = (const float*)d_in[1];
    const float* g1w  = (const float*)d_in[2];  const float* g1b  = (const float*)d_in[3];
    const float* be1w = (const float*)d_in[4];  const float* be1b = (const float*)d_in[5];
    const float* a1w  = (const float*)d_in[6];  const float* a1b  = (const float*)d_in[7];
    const float* g2w  = (const float*)d_in[8];  const float* g2b  = (const float*)d_in[9];
    const float* be2w = (const float*)d_in[10]; const float* be2b = (const float*)d_in[11];
    const float* a2w  = (const float*)d_in[12]; const float* a2b  = (const float*)d_in[13];
    const float* ln1g = (const float*)d_in[14]; const float* ln1b = (const float*)d_in[15];
    const float* ln2g = (const float*)d_in[16]; const float* ln2b = (const float*)d_in[17];
    const float* wq   = (const float*)d_in[18]; const float* bq   = (const float*)d_in[19];
    const float* wk   = (const float*)d_in[20]; const float* bk   = (const float*)d_in[21];
    const float* wv   = (const float*)d_in[22]; const float* bv   = (const float*)d_in[23];
    const float* lvw  = (const float*)d_in[24]; const float* lvb  = (const float*)d_in[25];
    const float* f1w  = (const float*)d_in[26]; const float* f1b  = (const float*)d_in[27];
    const float* f2w  = (const float*)d_in[28]; const float* f2b  = (const float*)d_in[29];
    (void)in_sizes; (void)n_in; (void)out_size; (void)ws_size;

    // workspace layout (bytes)
    char* w8 = (char*)d_ws;
    float*  mod  = (float*)(w8);                                   //  98304
    bf16_t* wqT  = (bf16_t*)(w8 + 98304);                          // 4096x512 bf16 (wq/wk/wv contiguous)
    bf16_t* lvwT = (bf16_t*)(w8 + 98304 + 3 * 4194304);            // 512x4096
    bf16_t* f1wT = (bf16_t*)(w8 + 98304 + 4 * 4194304);            // 2048x512
    bf16_t* f2wT = (bf16_t*)(w8 + 98304 + 4 * 4194304 + 2097152);  // 512x2048
    bf16_t* ybf  = (bf16_t*)(w8 + 98304 + 4 * 4194304 + 2 * 2097152);           // 8192x512
    bf16_t* qb   = (bf16_t*)(w8 + 98304 + 4 * 4194304 + 2 * 2097152 + 8388608); // (b,s,h,e); O in place
    bf16_t* kb   = qb + 33554432;    // (b,s,h,e)
    bf16_t* vtb  = kb + 33554432;    // V transposed: (b,h,e,s)

    (void)hipFuncSetAttribute((const void*)flash_kernel,
                              hipFuncAttributeMaxDynamicSharedMemorySize, FA_LDS);

    const dim3 blk(256);
    // weight transposes + modulation signals in one launch
    prep_kernel<<<10288, blk, 0, stream>>>(wq, wk, wv, lvw, f1w, f2w,
                                           wqT, lvwT, f1wT, f2wT,
                                           cond, g1w, be1w, a1w, g2w, be2w, a2w,
                                           g1b, be1b, a1b, g2b, be2b, a2b, mod);
    // LN1 + modulate -> y (bf16)
    ln_mod_kernel<<<8192, 128, 0, stream>>>(x, ln1g, ln1b, mod, mod + 4096, ybf);
    // fused QKV projection (V stored transposed), 256x128 tiles
    gemmqkv_kernel<<<dim3(96, 32), blk, 0, stream>>>(ybf, wqT, bq, bk, bv, qb, vtb);
    // fused flash attention: O overwrites qb
    flash_kernel<<<2048, 256, FA_LDS, stream>>>(qb, kb, vtb);
    // y2 = x + (O @ lvw + lvb) * alpha1 -> d_out (fp32)
    gemm64_kernel<<<dim3(4, 128), blk, 0, stream>>>(qb, lvwT, lvb, (float*)d_out, x, mod + 8192,
        8192, 512, 4096, 4096, 4096);
    // LN2 + modulate -> z (bf16)
    ln_mod_kernel<<<8192, 128, 0, stream>>>((const float*)d_out, ln2g, ln2b,
                                            mod + 12288, mod + 16384, ybf);
    // FFN
    gemm128_kernel<1><<<dim3(16, 64), blk, 0, stream>>>(ybf, f1wT, f1b, qb,
        8192, 2048, 512, 512, 512, 2048);
    gemm64_kernel<<<dim3(4, 128), blk, 0, stream>>>(qb, f2wT, f2b, (float*)d_out,
        (const float*)d_out, mod + 20480,
        8192, 512, 2048, 2048, 2048);
}

// Round 14
// 647.510 us; speedup vs baseline: 2.6219x; 1.1322x over previous
//
#include <hip/hip_runtime.h>
#include <hip/hip_bf16.h>

typedef __bf16 bf16_t;
typedef bf16_t bf16x8 __attribute__((ext_vector_type(8)));
typedef bf16_t bf16x4 __attribute__((ext_vector_type(4)));
typedef float f32x4 __attribute__((ext_vector_type(4)));

typedef const __attribute__((address_space(1))) void GV;
typedef __attribute__((address_space(3))) void LV;

__device__ __forceinline__ void gload_lds16(const bf16_t* gsrc, bf16_t* ldst) {
    __builtin_amdgcn_global_load_lds((GV*)gsrc, (LV*)ldst, 16, 0, 0);
}

// ---------------- prep: 6 weight transposes (bid<10240) + 6 modsig linears (bid>=10240)
__global__ __launch_bounds__(256) void prep_kernel(
    const float* __restrict__ wq, const float* __restrict__ wk, const float* __restrict__ wv,
    const float* __restrict__ lvw, const float* __restrict__ f1w, const float* __restrict__ f2w,
    bf16_t* __restrict__ wqT, bf16_t* __restrict__ lvwT,
    bf16_t* __restrict__ f1wT, bf16_t* __restrict__ f2wT,
    const float* __restrict__ cond,
    const float* __restrict__ mw0, const float* __restrict__ mw1, const float* __restrict__ mw2,
    const float* __restrict__ mw3, const float* __restrict__ mw4, const float* __restrict__ mw5,
    const float* __restrict__ mc0, const float* __restrict__ mc1, const float* __restrict__ mc2,
    const float* __restrict__ mc3, const float* __restrict__ mc4, const float* __restrict__ mc5,
    float* __restrict__ mod)
{
    __shared__ float sbuf[32 * 33];
    const int bid = blockIdx.x;
    if (bid < 10240) {
        float (*tile)[33] = (float(*)[33])sbuf;
        const float* in; bf16_t* out; int N, nx, K, local;
        if (bid < 6144) {
            const int sec = bid >> 11;
            local = bid & 2047;
            in = (sec == 0) ? wq : ((sec == 1) ? wk : wv);
            out = wqT + (long long)sec * 2097152;
            K = 512; N = 4096; nx = 128;
        } else if (bid < 8192) {
            local = bid - 6144; in = lvw; out = lvwT; K = 4096; N = 512; nx = 16;
        } else if (bid < 9216) {
            local = bid - 8192; in = f1w; out = f1wT; K = 512; N = 2048; nx = 64;
        } else {
            local = bid - 9216; in = f2w; out = f2wT; K = 2048; N = 512; nx = 16;
        }
        const int n0 = (local % nx) * 32, k0 = (local / nx) * 32;
        const int tx = threadIdx.x & 31, ty = threadIdx.x >> 5;
#pragma unroll
        for (int i = 0; i < 32; i += 8)
            tile[ty + i][tx] = in[(long long)(k0 + ty + i) * N + n0 + tx];
        __syncthreads();
#pragma unroll
        for (int i = 0; i < 32; i += 8)
            out[(long long)(n0 + ty + i) * K + k0 + tx] = (bf16_t)tile[tx][ty + i];
    } else {
        float* cs = sbuf;
        const int lb = bid - 10240;
        const int sig = lb >> 3, b = lb & 7;
        const float* w; const float* bi;
        switch (sig) {
            case 0: w = mw0; bi = mc0; break;
            case 1: w = mw1; bi = mc1; break;
            case 2: w = mw2; bi = mc2; break;
            case 3: w = mw3; bi = mc3; break;
            case 4: w = mw4; bi = mc4; break;
            default: w = mw5; bi = mc5; break;
        }
        for (int i = threadIdx.x; i < 512; i += 256) cs[i] = cond[b * 512 + i];
        __syncthreads();
        for (int n = threadIdx.x; n < 512; n += 256) {
            float s0 = 0.f, s1 = 0.f, s2 = 0.f, s3 = 0.f;
            for (int i = 0; i < 512; i += 4) {
                s0 = fmaf(cs[i], w[(long long)i * 512 + n], s0);
                s1 = fmaf(cs[i + 1], w[(long long)(i + 1) * 512 + n], s1);
                s2 = fmaf(cs[i + 2], w[(long long)(i + 2) * 512 + n], s2);
                s3 = fmaf(cs[i + 3], w[(long long)(i + 3) * 512 + n], s3);
            }
            mod[(long long)(sig * 8 + b) * 512 + n] = bi[n] + (s0 + s1) + (s2 + s3);
        }
    }
}

// ---------------- fused LayerNorm + AdaLN modulate, fp32 -> bf16
__global__ __launch_bounds__(128) void ln_mod_kernel(
    const float* __restrict__ x, const float* __restrict__ g, const float* __restrict__ be,
    const float* __restrict__ gamma, const float* __restrict__ beta, bf16_t* __restrict__ out)
{
    const int row = blockIdx.x;
    const int b = row >> 10;
    const int t = threadIdx.x;
    const float4 v = reinterpret_cast<const float4*>(x + (long long)row * 512)[t];
    float s = v.x + v.y + v.z + v.w;
    float ss = v.x * v.x + v.y * v.y + v.z * v.z + v.w * v.w;
    for (int o = 32; o; o >>= 1) { s += __shfl_xor(s, o); ss += __shfl_xor(ss, o); }
    __shared__ float red[4];
    if ((t & 63) == 0) { red[t >> 6] = s; red[2 + (t >> 6)] = ss; }
    __syncthreads();
    s = red[0] + red[1]; ss = red[2] + red[3];
    const float mu = s * (1.f / 512.f);
    const float rstd = rsqrtf(ss * (1.f / 512.f) - mu * mu + 1e-5f);
    const float4 gv = reinterpret_cast<const float4*>(g)[t];
    const float4 bv = reinterpret_cast<const float4*>(be)[t];
    const float4 ga = reinterpret_cast<const float4*>(gamma + b * 512)[t];
    const float4 bb = reinterpret_cast<const float4*>(beta + b * 512)[t];
    bf16x4 ov;
    ov[0] = (bf16_t)(((v.x - mu) * rstd * gv.x + bv.x) * (1.f + ga.x) + bb.x);
    ov[1] = (bf16_t)(((v.y - mu) * rstd * gv.y + bv.y) * (1.f + ga.y) + bb.y);
    ov[2] = (bf16_t)(((v.z - mu) * rstd * gv.z + bv.z) * (1.f + ga.z) + bb.z);
    ov[3] = (bf16_t)(((v.w - mu) * rstd * gv.w + bv.w) * (1.f + ga.w) + bb.w);
    reinterpret_cast<bf16x4*>(out + (long long)row * 512)[t] = ov;
}

// ---------------- 128x128x64 bf16 MFMA GEMM, dbuf single-barrier, XCD-swizzled
template <int EPI>
__global__ __launch_bounds__(256) void gemm128_kernel(
    const bf16_t* __restrict__ A, const bf16_t* __restrict__ B,
    const float* __restrict__ bias, void* Cout,
    int M, int N, int K, int lda, int ldb, int ldc)
{
    const int nbx = gridDim.x;
    const int lin = blockIdx.y * nbx + blockIdx.x;
    const int cpx = (nbx * gridDim.y) >> 3;
    const int swz = (lin & 7) * cpx + (lin >> 3);
    const int m0 = (swz / nbx) * 128, n0 = (swz % nbx) * 128;
    const int tid = threadIdx.x, lane = tid & 63, wid = tid >> 6;
    const int wr = wid >> 1, wc = wid & 1;

    __shared__ bf16_t As[16384];
    __shared__ bf16_t Bs[16384];

    f32x4 acc[4][4];
#pragma unroll
    for (int m = 0; m < 4; ++m)
#pragma unroll
        for (int n = 0; n < 4; ++n) acc[m][n] = (f32x4){0.f, 0.f, 0.f, 0.f};

    const int r8 = lane >> 3;
    const int lc = (lane & 7) ^ r8;
    long long aOff[4], bOff[4];
#pragma unroll
    for (int i = 0; i < 4; ++i) {
        const int row = i * 32 + wid * 8 + r8;
        aOff[i] = (long long)(m0 + row) * lda + lc * 8;
        bOff[i] = (long long)(n0 + row) * ldb + lc * 8;
    }

    const int frow = lane & 15, lg = lane >> 4;
    const int p0 = lg ^ (frow & 7);

#pragma unroll
    for (int i = 0; i < 4; ++i) gload_lds16(A + aOff[i], As + i * 2048 + wid * 512);
#pragma unroll
    for (int i = 0; i < 4; ++i) gload_lds16(B + bOff[i], Bs + i * 2048 + wid * 512);

    for (int kt = 0; kt < K; kt += 64) {
        const int cur = (kt >> 6) & 1;
        __syncthreads();
        if (kt + 64 < K) {
            const int nxt = (cur ^ 1) * 8192;
#pragma unroll
            for (int i = 0; i < 4; ++i) gload_lds16(A + aOff[i] + kt + 64, As + nxt + i * 2048 + wid * 512);
#pragma unroll
            for (int i = 0; i < 4; ++i) gload_lds16(B + bOff[i] + kt + 64, Bs + nxt + i * 2048 + wid * 512);
        }
        const bf16_t* Ab = As + cur * 8192;
        const bf16_t* Bb = Bs + cur * 8192;
        __builtin_amdgcn_s_setprio(1);
#pragma unroll
        for (int kk = 0; kk < 2; ++kk) {
            const int pc = p0 ^ (kk << 2);
            bf16x8 af[4], bfv[4];
#pragma unroll
            for (int m = 0; m < 4; ++m)
                af[m] = *reinterpret_cast<const bf16x8*>(Ab + (wr * 64 + m * 16 + frow) * 64 + pc * 8);
#pragma unroll
            for (int n = 0; n < 4; ++n)
                bfv[n] = *reinterpret_cast<const bf16x8*>(Bb + (wc * 64 + n * 16 + frow) * 64 + pc * 8);
#pragma unroll
            for (int m = 0; m < 4; ++m)
#pragma unroll
                for (int n = 0; n < 4; ++n)
                    acc[m][n] = __builtin_amdgcn_mfma_f32_16x16x32_bf16(af[m], bfv[n], acc[m][n], 0, 0, 0);
        }
        __builtin_amdgcn_s_setprio(0);
    }

#pragma unroll
    for (int m = 0; m < 4; ++m) {
        const int gm = m0 + wr * 64 + m * 16 + ((lane >> 4) << 2);
#pragma unroll
        for (int n = 0; n < 4; ++n) {
            const int gn = n0 + wc * 64 + n * 16 + (lane & 15);
            const float bb = bias ? bias[gn] : 0.f;
#pragma unroll
            for (int j = 0; j < 4; ++j) {
                const float v = acc[m][n][j] + bb;
                const int gmj = gm + j;
                if (EPI == 0) {
                    ((bf16_t*)Cout)[(long long)gmj * ldc + gn] = (bf16_t)v;
                } else {
                    ((bf16_t*)Cout)[(long long)gmj * ldc + gn] = (bf16_t)fmaxf(v, 0.f);
                }
            }
        }
    }
}

// ---------------- fused QKV GEMM (dbuf single-barrier, XCD-swizzled) — round-11 version
__global__ __launch_bounds__(256) void gemmqkv_kernel(
    const bf16_t* __restrict__ A, const bf16_t* __restrict__ B,
    const float* __restrict__ bq, const float* __restrict__ bk, const float* __restrict__ bv,
    bf16_t* __restrict__ qkv, bf16_t* __restrict__ vtb)
{
    const int lin = blockIdx.y * 96 + blockIdx.x;
    const int swz = (lin & 7) * 768 + (lin >> 3);
    const int m0 = (swz / 96) * 128, n0 = (swz % 96) * 128;
    const int sec = n0 >> 12;
    const float* bias = (sec == 0) ? bq : ((sec == 1) ? bk : bv);
    const int tid = threadIdx.x, lane = tid & 63, wid = tid >> 6;
    const int wr = wid >> 1, wc = wid & 1;

    __shared__ bf16_t As[16384];
    __shared__ bf16_t Bs[16384];

    f32x4 acc[4][4];
#pragma unroll
    for (int m = 0; m < 4; ++m)
#pragma unroll
        for (int n = 0; n < 4; ++n) acc[m][n] = (f32x4){0.f, 0.f, 0.f, 0.f};

    const int r8 = lane >> 3;
    const int lc = (lane & 7) ^ r8;
    long long aOff[4], bOff[4];
#pragma unroll
    for (int i = 0; i < 4; ++i) {
        const int row = i * 32 + wid * 8 + r8;
        aOff[i] = (long long)(m0 + row) * 512 + lc * 8;
        bOff[i] = (long long)(n0 + row) * 512 + lc * 8;
    }

    const int frow = lane & 15, lg = lane >> 4;
    const int p0 = lg ^ (frow & 7);

#pragma unroll
    for (int i = 0; i < 4; ++i) gload_lds16(A + aOff[i], As + i * 2048 + wid * 512);
#pragma unroll
    for (int i = 0; i < 4; ++i) gload_lds16(B + bOff[i], Bs + i * 2048 + wid * 512);

    for (int kt = 0; kt < 512; kt += 64) {
        const int cur = (kt >> 6) & 1;
        __syncthreads();
        if (kt + 64 < 512) {
            const int nxt = (cur ^ 1) * 8192;
#pragma unroll
            for (int i = 0; i < 4; ++i) gload_lds16(A + aOff[i] + kt + 64, As + nxt + i * 2048 + wid * 512);
#pragma unroll
            for (int i = 0; i < 4; ++i) gload_lds16(B + bOff[i] + kt + 64, Bs + nxt + i * 2048 + wid * 512);
        }
        const bf16_t* Ab = As + cur * 8192;
        const bf16_t* Bb = Bs + cur * 8192;
        __builtin_amdgcn_s_setprio(1);
#pragma unroll
        for (int kk = 0; kk < 2; ++kk) {
            const int pc = p0 ^ (kk << 2);
            bf16x8 af[4], bfv[4];
#pragma unroll
            for (int m = 0; m < 4; ++m)
                af[m] = *reinterpret_cast<const bf16x8*>(Ab + (wr * 64 + m * 16 + frow) * 64 + pc * 8);
#pragma unroll
            for (int n = 0; n < 4; ++n)
                bfv[n] = *reinterpret_cast<const bf16x8*>(Bb + (wc * 64 + n * 16 + frow) * 64 + pc * 8);
#pragma unroll
            for (int m = 0; m < 4; ++m)
#pragma unroll
                for (int n = 0; n < 4; ++n)
                    acc[m][n] = __builtin_amdgcn_mfma_f32_16x16x32_bf16(af[m], bfv[n], acc[m][n], 0, 0, 0);
        }
        __builtin_amdgcn_s_setprio(0);
    }

#pragma unroll
    for (int m = 0; m < 4; ++m) {
        const int gm = m0 + wr * 64 + m * 16 + ((lane >> 4) << 2);
#pragma unroll
        for (int n = 0; n < 4; ++n) {
            const int gn = n0 + wc * 64 + n * 16 + (lane & 15);
            const int gnl = gn & 4095;
            const float bb = bias[gnl];
#pragma unroll
            for (int j = 0; j < 4; ++j) {
                const float v = acc[m][n][j] + bb;
                const int gmj = gm + j;
                if (sec < 2) {
                    qkv[(long long)sec * 33554432 + (long long)gmj * 4096 + gnl] = (bf16_t)v;
                } else {
                    const long long ci =
                        (long long)(((gmj >> 10) * 8 + (gnl >> 9)) * 512 + (gnl & 511)) * 1024 + (gmj & 1023);
                    vtb[ci] = (bf16_t)v;
                }
            }
        }
    }
}

// ---------------- 64x128x64 GEMM (dbuf single-barrier, XCD-swizzled)
__global__ __launch_bounds__(256) void gemm64_kernel(
    const bf16_t* __restrict__ A, const bf16_t* __restrict__ B,
    const float* __restrict__ bias, float* __restrict__ Cout,
    const float* __restrict__ resid, const float* __restrict__ alpha,
    int M, int N, int K, int lda, int ldb)
{
    const int nbx = gridDim.x;
    const int lin = blockIdx.y * nbx + blockIdx.x;
    const int cpx = (nbx * gridDim.y) >> 3;
    const int swz = (lin & 7) * cpx + (lin >> 3);
    const int m0 = (swz / nbx) * 64, n0 = (swz % nbx) * 128;
    const int tid = threadIdx.x, lane = tid & 63, wid = tid >> 6;
    const int wr = wid >> 1, wc = wid & 1;

    __shared__ bf16_t As[8192];
    __shared__ bf16_t Bs[16384];

    f32x4 acc[2][4];
#pragma unroll
    for (int m = 0; m < 2; ++m)
#pragma unroll
        for (int n = 0; n < 4; ++n) acc[m][n] = (f32x4){0.f, 0.f, 0.f, 0.f};

    const int r8 = lane >> 3;
    const int lc = (lane & 7) ^ r8;
    long long aOff[2], bOff[4];
#pragma unroll
    for (int i = 0; i < 2; ++i)
        aOff[i] = (long long)(m0 + i * 32 + wid * 8 + r8) * lda + lc * 8;
#pragma unroll
    for (int i = 0; i < 4; ++i)
        bOff[i] = (long long)(n0 + i * 32 + wid * 8 + r8) * ldb + lc * 8;

    const int frow = lane & 15, lg = lane >> 4;
    const int p0 = lg ^ (frow & 7);

#pragma unroll
    for (int i = 0; i < 2; ++i) gload_lds16(A + aOff[i], As + i * 2048 + wid * 512);
#pragma unroll
    for (int i = 0; i < 4; ++i) gload_lds16(B + bOff[i], Bs + i * 2048 + wid * 512);

    for (int kt = 0; kt < K; kt += 64) {
        const int cur = (kt >> 6) & 1;
        __syncthreads();
        if (kt + 64 < K) {
#pragma unroll
            for (int i = 0; i < 2; ++i)
                gload_lds16(A + aOff[i] + kt + 64, As + (cur ^ 1) * 4096 + i * 2048 + wid * 512);
#pragma unroll
            for (int i = 0; i < 4; ++i)
                gload_lds16(B + bOff[i] + kt + 64, Bs + (cur ^ 1) * 8192 + i * 2048 + wid * 512);
        }
        const bf16_t* Ab = As + cur * 4096;
        const bf16_t* Bb = Bs + cur * 8192;
        __builtin_amdgcn_s_setprio(1);
#pragma unroll
        for (int kk = 0; kk < 2; ++kk) {
            const int pc = p0 ^ (kk << 2);
            bf16x8 af[2], bfv[4];
#pragma unroll
            for (int m = 0; m < 2; ++m)
                af[m] = *reinterpret_cast<const bf16x8*>(Ab + (wr * 32 + m * 16 + frow) * 64 + pc * 8);
#pragma unroll
            for (int n = 0; n < 4; ++n)
                bfv[n] = *reinterpret_cast<const bf16x8*>(Bb + (wc * 64 + n * 16 + frow) * 64 + pc * 8);
#pragma unroll
            for (int m = 0; m < 2; ++m)
#pragma unroll
                for (int n = 0; n < 4; ++n)
                    acc[m][n] = __builtin_amdgcn_mfma_f32_16x16x32_bf16(af[m], bfv[n], acc[m][n], 0, 0, 0);
        }
        __builtin_amdgcn_s_setprio(0);
    }

#pragma unroll
    for (int m = 0; m < 2; ++m) {
        const int gm = m0 + wr * 32 + m * 16 + ((lane >> 4) << 2);
#pragma unroll
        for (int n = 0; n < 4; ++n) {
            const int gn = n0 + wc * 64 + n * 16 + (lane & 15);
            const float bb = bias[gn];
#pragma unroll
            for (int j = 0; j < 4; ++j) {
                const int gmj = gm + j;
                const long long ci = (long long)gmj * 512 + gn;
                Cout[ci] = resid[ci] + (acc[m][n][j] + bb) * alpha[(gmj >> 10) * 512 + gn];
            }
        }
    }
}

// ---------------- fused flash attention v10 = round-11 v7 + T13 defer-max (THR=8)
// mS (P-exponent) and mP (acc offset) follow the identical per-row recurrence, so
// deferring both with the same row-local predicate keeps them equal; P <= 2^8, and
// the shared offset cancels in O = acc/l.
#define FA_LDS 69632
#define SCL 0.04508422132207354f   /* (1/32) * log2(e) */
#define DTHR 8.0f
__global__ __launch_bounds__(256, 2) void flash_kernel(
    bf16_t* __restrict__ qb, const bf16_t* __restrict__ kb, const bf16_t* __restrict__ vtb)
{
    extern __shared__ char smem[];
    bf16_t* Ks = (bf16_t*)smem;               // [32][512], chunk16 ^ (row&7)
    bf16_t* Vs = (bf16_t*)(smem + 32768);     // [512][32], chunk16 ^ ((e>>1)&3)
    char* PB = smem + 65536;                  // [32 q][32 k]; granule g: chunk (g>>1)^((q>>1)&3), half g&1
    float* pmaxB = (float*)(smem + 67584);    // [2][32 q][2 wk]
    float* psumB = (float*)(smem + 68608);    // [2][32 q][2 wk]

    const int bid = blockIdx.x;
    const int xcd = bid & 7, idx = bid >> 3;
    const int qt = idx & 31, bhl = idx >> 5;
    const int bh = xcd * 8 + bhl;
    const int b = bh >> 3, h = bh & 7;
    const int q0 = qt * 32;
    const int tid = threadIdx.x, lane = tid & 63, wid = tid >> 6;  // 4 waves
    const int laneq = lane & 15, lx = lane & 7, lg = lane >> 4;
    const int wk = wid >> 1, wq = wid & 1;    // S role: k-half, q-half
    const int we = wid;                       // PV role: e-quarter

    // ---- prologue: stage K(0); Q frags to registers
#pragma unroll
    for (int r = 0; r < 8; ++r) {
        const int row = r * 4 + wid;
        gload_lds16(kb + ((long long)(b * 1024 + row) * 8 + h) * 512 + ((lane ^ (row & 7)) << 3),
                    Ks + row * 512);
    }
    const int qi = wq * 16 + laneq;
    bf16x8 qfrag[16];
    {
        const bf16_t* qrow = qb + ((long long)(b * 1024 + q0 + qi) * 8 + h) * 512 + lg * 8;
#pragma unroll
        for (int ks = 0; ks < 16; ++ks) qfrag[ks] = *reinterpret_cast<const bf16x8*>(qrow + ks * 32);
    }
    f32x4 accA[8], accB[8];
#pragma unroll
    for (int e = 0; e < 8; ++e) { accA[e] = (f32x4){0.f,0.f,0.f,0.f}; accB[e] = (f32x4){0.f,0.f,0.f,0.f}; }
    float mS = 0.f, mPA = 0.f, mPB = 0.f, lA = 0.f, lB = 0.f;
    const int rA = wk * 16 + laneq;           // K LDS row for S-phase
    const int qA = laneq, qB = laneq + 16;    // PV-role q rows
    __syncthreads();

    for (int t = 0; t < 32; ++t) {
        // (a) issue V(t) staging — hidden under S-phase
#pragma unroll
        for (int r = 0; r < 8; ++r) {
            const int e0 = (r * 4 + wid) * 16;
            const int e = e0 + (lane >> 2);
            gload_lds16(vtb + ((long long)bh * 512 + e) * 1024 + t * 32
                            + (((lane & 3) ^ ((e >> 1) & 3)) << 3),
                        Vs + e0 * 32);
        }
        // (b) S-phase: S^T tile = K · Q^T (16 MFMAs)
        f32x4 s0 = (f32x4){0.f, 0.f, 0.f, 0.f};
        const char* KsB = (const char*)Ks;
        __builtin_amdgcn_s_setprio(1);
#pragma unroll
        for (int ks = 0; ks < 16; ++ks) {
            const int co = (((ks * 4 + lg) ^ lx) << 4);
            bf16x8 a0 = *(const bf16x8*)(KsB + rA * 1024 + co);
            s0 = __builtin_amdgcn_mfma_f32_16x16x32_bf16(a0, qfrag[ks], s0, 0, 0, 0);
        }
        __builtin_amdgcn_s_setprio(0);
        // (c) deferred-max softmax partials + P write
        float f[4], pe[4];
#pragma unroll
        for (int j = 0; j < 4; ++j) f[j] = s0[j] * SCL;
        float mloc = fmaxf(fmaxf(f[0], f[1]), fmaxf(f[2], f[3]));
        mloc = fmaxf(mloc, __shfl_xor(mloc, 16));
        mloc = fmaxf(mloc, __shfl_xor(mloc, 32));
        float sl = 0.f;
#pragma unroll
        for (int j = 0; j < 4; ++j) { pe[j] = exp2f(f[j] - mS); sl += pe[j]; }
        sl += __shfl_xor(sl, 16);
        sl += __shfl_xor(sl, 32);
        if (lane < 16) {
            const int si = (t & 1) * 64 + (wq * 16 + lane) * 2 + wk;
            pmaxB[si] = mloc;
            psumB[si] = sl;
        }
        {
            bf16x4 p;
#pragma unroll
            for (int j = 0; j < 4; ++j) p[j] = (bf16_t)pe[j];
            const int g = wk * 4 + lg;
            *(bf16x4*)(PB + qi * 64 + ((((g >> 1) ^ ((qi >> 1) & 3))) << 4) + ((g & 1) << 3)) = p;
        }
        __syncthreads();  // (d): V(t)+P+stats ready (vmcnt drained)

        // (e) issue K(t+1) staging — hidden under PV-phase
        if (t < 31) {
#pragma unroll
            for (int r = 0; r < 8; ++r) {
                const int row = r * 4 + wid;
                gload_lds16(kb + ((long long)(b * 1024 + t * 32 + 32 + row) * 8 + h) * 512
                                + ((lane ^ (row & 7)) << 3),
                            Ks + row * 512);
            }
        }
        // (f) PV: 16 MFMAs (K=32 in one MFMA per e-tile)
        const char* VB = (const char*)Vs;
        bf16x8 pA = *(const bf16x8*)(PB + qA * 64 + ((lg ^ ((qA >> 1) & 3)) << 4));
        bf16x8 pBv = *(const bf16x8*)(PB + qB * 64 + ((lg ^ ((qB >> 1) & 3)) << 4));
        __builtin_amdgcn_s_setprio(1);
#pragma unroll
        for (int ef = 0; ef < 8; ++ef) {
            const int re = we * 128 + ef * 16 + laneq;
            bf16x8 av = *(const bf16x8*)(VB + re * 64 + ((lg ^ ((re >> 1) & 3)) << 4));
            accA[ef] = __builtin_amdgcn_mfma_f32_16x16x32_bf16(av, pA, accA[ef], 0, 0, 0);
            accB[ef] = __builtin_amdgcn_mfma_f32_16x16x32_bf16(av, pBv, accB[ef], 0, 0, 0);
        }
        __builtin_amdgcn_s_setprio(0);
        // stats: paired reads; defer m-update until growth > DTHR (row-local predicate,
        // identical recurrence for mS and mP keeps S/PV offsets equal)
        {
            const float* pmax_t = pmaxB + (t & 1) * 64;
            const float* psum_t = psumB + (t & 1) * 64;
            const float2 pmA = *(const float2*)&pmax_t[qA * 2];
            const float2 pmB = *(const float2*)&pmax_t[qB * 2];
            const float2 psA = *(const float2*)&psum_t[qA * 2];
            const float2 psB = *(const float2*)&psum_t[qB * 2];
            const float rmS = wq ? fmaxf(pmB.x, pmB.y) : fmaxf(pmA.x, pmA.y);
            if (rmS > mS + DTHR) mS = rmS;
            lA += psA.x + psA.y;
            lB += psB.x + psB.y;
            const float rmA = fmaxf(pmA.x, pmA.y);
            const float rmB = fmaxf(pmB.x, pmB.y);
            const bool needA = rmA > mPA + DTHR;
            const bool needB = rmB > mPB + DTHR;
            if (__ballot(needA || needB)) {
                const float mnA = needA ? rmA : mPA;
                const float mnB = needB ? rmB : mPB;
                const float rsA = exp2f(mPA - mnA), rsB = exp2f(mPB - mnB);
                lA *= rsA; lB *= rsB;
#pragma unroll
                for (int e = 0; e < 8; ++e) {
#pragma unroll
                    for (int j = 0; j < 4; ++j) { accA[e][j] *= rsA; accB[e][j] *= rsB; }
                }
                mPA = mnA; mPB = mnB;
            }
        }
        __syncthreads();  // (g): K(t+1) ready; P/V reads done
    }

    // ---- epilogue: O = acc / l, store over qb (shared offset cancels)
    const float iA = 1.f / lA, iB = 1.f / lB;
#pragma unroll
    for (int ef = 0; ef < 8; ++ef) {
        const int e0 = we * 128 + ef * 16 + lg * 4;
        bf16x4 oA, oB;
#pragma unroll
        for (int j = 0; j < 4; ++j) { oA[j] = (bf16_t)(accA[ef][j] * iA); oB[j] = (bf16_t)(accB[ef][j] * iB); }
        *(bf16x4*)(qb + ((long long)(b * 1024 + q0 + qA) * 8 + h) * 512 + e0) = oA;
        *(bf16x4*)(qb + ((long long)(b * 1024 + q0 + qB) * 8 + h) * 512 + e0) = oB;
    }
}

extern "C" void kernel_launch(void* const* d_in, const int* in_sizes, int n_in,
                              void* d_out, int out_size, void* d_ws, size_t ws_size,
                              hipStream_t stream)
{
    const float* x    = (const float*)d_in[0];
    const float* cond = (const float*)d_in[1];
    const float* g1w  = (const float*)d_in[2];  const float* g1b  = (const float*)d_in[3];
    const float* be1w = (const float*)d_in[4];  const float* be1b = (const float*)d_in[5];
    const float* a1w  = (const float*)d_in[6];  const float* a1b  = (const float*)d_in[7];
    const float* g2w  = (const float*)d_in[8];  const float* g2b  = (const float*)d_in[9];
    const float* be2w = (const float*)d_in[10]; const float* be2b = (const float*)d_in[11];
    const float* a2w  = (const float*)d_in[12]; const float* a2b  = (const float*)d_in[13];
    const float* ln1g = (const float*)d_in[14]; const float* ln1b = (const float*)d_in[15];
    const float* ln2g = (const float*)d_in[16]; const float* ln2b = (const float*)d_in[17];
    const float* wq   = (const float*)d_in[18]; const float* bq   = (const float*)d_in[19];
    const float* wk   = (const float*)d_in[20]; const float* bk   = (const float*)d_in[21];
    const float* wv   = (const float*)d_in[22]; const float* bv   = (const float*)d_in[23];
    const float* lvw  = (const float*)d_in[24]; const float* lvb  = (const float*)d_in[25];
    const float* f1w  = (const float*)d_in[26]; const float* f1b  = (const float*)d_in[27];
    const float* f2w  = (const float*)d_in[28]; const float* f2b  = (const float*)d_in[29];
    (void)in_sizes; (void)n_in; (void)out_size; (void)ws_size;

    // workspace layout (bytes)
    char* w8 = (char*)d_ws;
    float*  mod  = (float*)(w8);                                   //  98304
    bf16_t* wqT  = (bf16_t*)(w8 + 98304);                          // 4096x512 bf16 (wq/wk/wv contiguous)
    bf16_t* lvwT = (bf16_t*)(w8 + 98304 + 3 * 4194304);            // 512x4096
    bf16_t* f1wT = (bf16_t*)(w8 + 98304 + 4 * 4194304);            // 2048x512
    bf16_t* f2wT = (bf16_t*)(w8 + 98304 + 4 * 4194304 + 2097152);  // 512x2048
    bf16_t* ybf  = (bf16_t*)(w8 + 98304 + 4 * 4194304 + 2 * 2097152);           // 8192x512
    bf16_t* qb   = (bf16_t*)(w8 + 98304 + 4 * 4194304 + 2 * 2097152 + 8388608); // (b,s,h,e); O in place
    bf16_t* kb   = qb + 33554432;    // (b,s,h,e)
    bf16_t* vtb  = kb + 33554432;    // V transposed: (b,h,e,s)

    (void)hipFuncSetAttribute((const void*)flash_kernel,
                              hipFuncAttributeMaxDynamicSharedMemorySize, FA_LDS);

    const dim3 blk(256);
    // weight transposes + modulation signals in one launch
    prep_kernel<<<10288, blk, 0, stream>>>(wq, wk, wv, lvw, f1w, f2w,
                                           wqT, lvwT, f1wT, f2wT,
                                           cond, g1w, be1w, a1w, g2w, be2w, a2w,
                                           g1b, be1b, a1b, g2b, be2b, a2b, mod);
    // LN1 + modulate -> y (bf16)
    ln_mod_kernel<<<8192, 128, 0, stream>>>(x, ln1g, ln1b, mod, mod + 4096, ybf);
    // fused QKV projection (V stored transposed)
    gemmqkv_kernel<<<dim3(96, 64), blk, 0, stream>>>(ybf, wqT, bq, bk, bv, qb, vtb);
    // fused flash attention: O overwrites qb
    flash_kernel<<<2048, 256, FA_LDS, stream>>>(qb, kb, vtb);
    // y2 = x + (O @ lvw + lvb) * alpha1 -> d_out (fp32)
    gemm64_kernel<<<dim3(4, 128), blk, 0, stream>>>(qb, lvwT, lvb, (float*)d_out, x, mod + 8192,
        8192, 512, 4096, 4096, 4096);
    // LN2 + modulate -> z (bf16)
    ln_mod_kernel<<<8192, 128, 0, stream>>>((const float*)d_out, ln2g, ln2b,
                                            mod + 12288, mod + 16384, ybf);
    // FFN
    gemm128_kernel<1><<<dim3(16, 64), blk, 0, stream>>>(ybf, f1wT, f1b, qb,
        8192, 2048, 512, 512, 512, 2048);
    gemm64_kernel<<<dim3(4, 128), blk, 0, stream>>>(qb, f2wT, f2b, (float*)d_out,
        (const float*)d_out, mod + 20480,
        8192, 512, 2048, 2048, 2048);
}